// Round 4
// baseline (1151.685 us; speedup 1.0000x reference)
//
#include <hip/hip_runtime.h>
#include <cstdint>
#include <cstddef>

// DigitCapsules routing: B=256, R=1152, C=10, IC=8, OC=16, 3 iters.
// R4: recompute u on the fly; thread = (b, r) owns ALL 160 (c,o):
//   - softmax/logits 100% thread-local (no shuffles)
//   - wave = 64 b's @ one r -> W is wave-uniform -> scalar s_load path
//   - x pre-transposed to xT[r][b][i] for coalesced per-wave loads
//   - r-reduce: ds_add_f32 into block-local s, flush non-atomic partials,
//     tiny reduce+squash kernel. ZERO global atomics.
// Logits linear in v (b_t = u.(v1+..+v_{t-1})) -> running vsum, 1 pass/iter.
#define NB 256
#define NR 1152
#define NC 10
#define NI 8
#define NO 16
#define RGRPS 144   // r-groups (8 r per block)
#define GPASS 576   // RGRPS * 4 b-tiles

static __device__ __forceinline__ uint32_t bf16_pack2(float lo, float hi) {
    uint32_t vl = __float_as_uint(lo);
    vl = vl + 0x7FFFu + ((vl >> 16) & 1u);
    uint32_t vh = __float_as_uint(hi);
    vh = vh + 0x7FFFu + ((vh >> 16) & 1u);
    return (vl >> 16) | (vh & 0xFFFF0000u);
}

// -------------------------------------------------------------------------
// x transpose: x[b][r][i] -> xT[r][b][i]. Block = 64 b x 16 r. 288 blocks.
__global__ __launch_bounds__(256) void caps_xt_kernel(
    const float* __restrict__ x, float* __restrict__ xT)
{
    const int rt = blockIdx.x >> 2;   // 0..71
    const int bt = blockIdx.x & 3;
    const int b0 = bt * 64, r0 = rt * 16;
    const int t  = threadIdx.x;
    __shared__ float tile[64][16][9];   // +1 pad

    for (int k4 = t; k4 < 2048; k4 += 256) {
        const int bi = k4 >> 5, rem = k4 & 31;
        const int rr = rem >> 1, hf = rem & 1;
        const float4 v = *(const float4*)&x[((size_t)(b0 + bi) * NR + r0 + rr) * 8 + hf * 4];
        float* d = &tile[bi][rr][hf * 4];
        d[0] = v.x; d[1] = v.y; d[2] = v.z; d[3] = v.w;
    }
    __syncthreads();
    for (int k4 = t; k4 < 2048; k4 += 256) {
        const int rr = k4 >> 7, rem = k4 & 127;
        const int bi = rem >> 1, hf = rem & 1;
        const float* sp = &tile[bi][rr][hf * 4];
        const float4 v = {sp[0], sp[1], sp[2], sp[3]};
        *(float4*)&xT[((size_t)(r0 + rr) * NB + b0 + bi) * 8 + hf * 4] = v;
    }
}

// -------------------------------------------------------------------------
// One routing pass. Block: 256 thr = 4 waves x 64 b-lanes; 2 r's per wave
// (8 r per block). Writes partial s to part[rg][b][160] (no atomics).
// mode 0: wgt = 0.1 uniform (iter 1). mode 1: wgt = softmax_c(u . vsum).
__global__ __launch_bounds__(256, 2) void caps_pass_kernel(
    const float* __restrict__ xT, const float* __restrict__ W,
    const float* __restrict__ vsum, float* __restrict__ part, const int mode)
{
    const int rg = blockIdx.x >> 2;   // 0..143
    const int bt = blockIdx.x & 3;
    const int b0 = bt * 64;
    const int t  = threadIdx.x;
    const int w  = t >> 6;            // wave 0..3
    const int bl = t & 63;
    const int b  = b0 + bl;

    __shared__ uint32_t vss[64][81];  // bf16-packed vsum, [b][pair]; 81: 2-way max
    __shared__ float   sblk[64][161]; // fp32 s accumulator; 161: 2-way max

    for (int k = t; k < 64 * 161; k += 256) ((float*)sblk)[k] = 0.f;
    if (mode != 0) {
        const float2* vp = (const float2*)(vsum + (size_t)b0 * 160);
        for (int k = t; k < 64 * 80; k += 256) {
            const float2 v = vp[k];
            const int bi = k / 80, j = k - bi * 80;
            vss[bi][j] = bf16_pack2(v.x, v.y);
        }
    }
    __syncthreads();

    for (int ri = 0; ri < 2; ++ri) {
        const int r  = rg * 8 + ri * 4 + w;
        const int ru = __builtin_amdgcn_readfirstlane(r);   // wave-uniform!

        const float4* xp = (const float4*)(xT + ((size_t)r * NB + b) * 8);
        const float4 xa = xp[0], xb = xp[1];
        const float xr[8] = {xa.x, xa.y, xa.z, xa.w, xb.x, xb.y, xb.z, xb.w};

        const float* wr = W + (size_t)ru * (NC * NI * NO);  // uniform -> s_load
        float u[NC][NO];
#pragma unroll
        for (int c = 0; c < NC; ++c) {
#pragma unroll
            for (int o = 0; o < NO; ++o) u[c][o] = 0.f;
#pragma unroll
            for (int i = 0; i < NI; ++i) {
                const float* wci = wr + (c * NI + i) * NO;
                const float xv = xr[i];
#pragma unroll
                for (int o = 0; o < NO; ++o) u[c][o] = fmaf(xv, wci[o], u[c][o]);
            }
        }

        float wgt[NC];
        if (mode != 0) {
            float lg[NC];
#pragma unroll
            for (int c = 0; c < NC; ++c) {
                float a = 0.f;
#pragma unroll
                for (int k = 0; k < 8; ++k) {
                    const uint32_t pw = vss[bl][c * 8 + k];
                    a = fmaf(__uint_as_float(pw << 16),         u[c][2 * k],     a);
                    a = fmaf(__uint_as_float(pw & 0xFFFF0000u), u[c][2 * k + 1], a);
                }
                lg[c] = a;
            }
            float m = lg[0];
#pragma unroll
            for (int c = 1; c < NC; ++c) m = fmaxf(m, lg[c]);
            float ssum = 0.f;
#pragma unroll
            for (int c = 0; c < NC; ++c) { wgt[c] = __expf(lg[c] - m); ssum += wgt[c]; }
            const float inv = 1.f / ssum;
#pragma unroll
            for (int c = 0; c < NC; ++c) wgt[c] *= inv;
        } else {
#pragma unroll
            for (int c = 0; c < NC; ++c) wgt[c] = 0.1f;
        }

        // LDS accumulate (ds_add_f32; banks = (bl+j)%32 -> 2-way max = free)
#pragma unroll
        for (int c = 0; c < NC; ++c)
#pragma unroll
            for (int o = 0; o < NO; ++o)
                atomicAdd(&sblk[bl][c * 16 + o], wgt[c] * u[c][o]);
    }
    __syncthreads();

    // flush block partial: part[rg][b0..b0+64][0..159] (fully contiguous)
    float* pdst = part + ((size_t)rg * NB + b0) * 160;
    for (int k = t; k < 64 * 160; k += 256) {
        const int bi = k >> 7;               // k/160? no: use exact
        const int bi2 = k / 160, j = k - bi2 * 160;
        (void)bi;
        pdst[k] = sblk[bi2][j];
    }
}

// -------------------------------------------------------------------------
// reduce 144 partials + squash. grid=256 (b), 192 thr (160 active).
// mode 0: vsum = v ; 1: vsum += v ; 2: out = v
__global__ __launch_bounds__(192) void caps_reduce_kernel(
    const float* __restrict__ part, float* __restrict__ vsum,
    float* __restrict__ out, const int mode)
{
    const int b = blockIdx.x;
    const int t = threadIdx.x;
    if (t >= 160) return;
    float s0 = 0.f, s1 = 0.f, s2 = 0.f, s3 = 0.f;
    const float* p = part + (size_t)b * 160 + t;
#pragma unroll 4
    for (int g = 0; g < RGRPS; g += 4) {
        s0 += p[(size_t)(g + 0) * NB * 160];
        s1 += p[(size_t)(g + 1) * NB * 160];
        s2 += p[(size_t)(g + 2) * NB * 160];
        s3 += p[(size_t)(g + 3) * NB * 160];
    }
    const float s = (s0 + s1) + (s2 + s3);
    float n2 = s * s;
    n2 += __shfl_xor(n2, 1);
    n2 += __shfl_xor(n2, 2);
    n2 += __shfl_xor(n2, 4);
    n2 += __shfl_xor(n2, 8);
    const float nrm   = sqrtf(n2);
    const float scale = n2 / (1.f + n2) / (nrm + 1e-8f);
    const float v = scale * s;
    if (mode == 0)      vsum[(size_t)b * 160 + t] = v;
    else if (mode == 1) vsum[(size_t)b * 160 + t] += v;
    else                out[(size_t)b * 160 + t] = v;
}

// -------------------------------------------------------------------------
extern "C" void kernel_launch(void* const* d_in, const int* in_sizes, int n_in,
                              void* d_out, int out_size, void* d_ws, size_t ws_size,
                              hipStream_t stream) {
    const float* x = (const float*)d_in[0];   // [256,1152,8]
    const float* W = (const float*)d_in[1];   // [1,1152,10,8,16]
    float* out = (float*)d_out;               // [256,10,16]

    // ws: xT 9,437,184 B | part 144*256*160*4 = 23,592,960 B | vsum 163,840 B
    uint8_t* ws = (uint8_t*)d_ws;
    float* xT  = (float*)(ws);
    float* prt = (float*)(ws + 9437184u);
    float* vsm = (float*)(ws + 9437184u + 23592960u);

    caps_xt_kernel    <<< 288, 256, 0, stream>>>(x, xT);
    caps_pass_kernel  <<<GPASS, 256, 0, stream>>>(xT, W, vsm, prt, 0);
    caps_reduce_kernel<<< 256, 192, 0, stream>>>(prt, vsm, nullptr, 0);
    caps_pass_kernel  <<<GPASS, 256, 0, stream>>>(xT, W, vsm, prt, 1);
    caps_reduce_kernel<<< 256, 192, 0, stream>>>(prt, vsm, nullptr, 1);
    caps_pass_kernel  <<<GPASS, 256, 0, stream>>>(xT, W, vsm, prt, 1);
    caps_reduce_kernel<<< 256, 192, 0, stream>>>(prt, nullptr, out, 2);
}

// Round 5
// 297.670 us; speedup vs baseline: 3.8690x; 3.8690x over previous
//
#include <hip/hip_runtime.h>
#include <cstdint>
#include <cstddef>

// DigitCapsules routing: B=256, R=1152, C=10, IC=8, OC=16, 3 iters.
// R5 (4 launches):
//   1. caps_u: u[b][c][r][o] bf16 (94 MB). thread=(c,r,o-half): W=64 regs,
//      b-loop 32, x LDS-staged (HBM-read once). Wave stores contiguous 512 B.
//   2-4. caps_fused (mode 0/1/2): block = one b, 1024 thr = 256 rl x 4 oq.
//      One u-read per pass; logits via 4-o thread dot + 2 shuffles; softmax
//      thread-local; r-reduce in-block; squash fused into epilogue.
// Register discipline (R2/R4 lesson): fused kernel keeps ~85 live VGPRs
// (acc 40 + packed q 20 + lg 10); v lives in LDS (ds_read_b128 broadcast).
// Logits are linear in v: b_t = u.(v1+..+v_{t-1}) -> running vsum.
#define NB 256
#define NR 1152
#define NC 10
#define NI 8
#define NO 16

static __device__ __forceinline__ uint32_t bf16_pack2(float lo, float hi) {
    uint32_t vl = __float_as_uint(lo);
    vl = vl + 0x7FFFu + ((vl >> 16) & 1u);
    uint32_t vh = __float_as_uint(hi);
    vh = vh + 0x7FFFu + ((vh >> 16) & 1u);
    return (vl >> 16) | (vh & 0xFFFF0000u);
}

// -------------------------------------------------------------------------
// caps_u: grid 576 = 8 b-groups x 72 r-chunks (rc = blockIdx%72 so the 8
// same-rc siblings land on ONE XCD -> W slice cached once per XCD L2).
// block 320: t -> c = t/32, rl = (t&31)>>1, oh = t&1. W slice (all i, 8 o's)
// = 16 float4 in regs, reused across 32-deep b-loop. x staged in LDS.
__global__ __launch_bounds__(320, 4) void caps_u_kernel(
    const float* __restrict__ x, const float* __restrict__ W,
    uint32_t* __restrict__ u)
{
    const int rc  = blockIdx.x % 72;
    const int bg  = blockIdx.x / 72;    // 0..7
    const int b0  = bg * 32;
    const int t   = threadIdx.x;
    const int c   = t >> 5;             // 0..9
    const int w32 = t & 31;
    const int rl  = w32 >> 1;           // 0..15
    const int oh  = w32 & 1;            // o-half
    const int r   = rc * 16 + rl;

    __shared__ float xs[32][16][9];     // +1 pad

    // stage x[b0..b0+32)[r-chunk][8] : 1024 float4 loads, coalesced
    for (int k = t; k < 1024; k += 320) {
        const int bi = k >> 5, rem = k & 31;
        const int rr = rem >> 1, hf = rem & 1;
        const float4 v = *(const float4*)(
            x + ((size_t)(b0 + bi) * NR + rc * 16 + rr) * 8 + hf * 4);
        float* d = &xs[bi][rr][hf * 4];
        d[0] = v.x; d[1] = v.y; d[2] = v.z; d[3] = v.w;
    }

    // W[r][c][i][oh*8 + 0..7] -> 16 float4 in registers
    float4 wf[16];
    const float* wb = W + ((size_t)r * NC + c) * (NI * NO) + oh * 8;
#pragma unroll
    for (int i = 0; i < 8; ++i) {
        wf[i * 2 + 0] = *(const float4*)(wb + i * NO);
        wf[i * 2 + 1] = *(const float4*)(wb + i * NO + 4);
    }
    __syncthreads();

    for (int bi = 0; bi < 32; ++bi) {
        const int b = b0 + bi;
        float xr[8];
#pragma unroll
        for (int i = 0; i < 8; ++i) xr[i] = xs[bi][rl][i];
        float a[8];
#pragma unroll
        for (int j = 0; j < 8; ++j) a[j] = 0.f;
#pragma unroll
        for (int i = 0; i < 8; ++i) {
            const float xv = xr[i];
            const float4 w0 = wf[i * 2 + 0], w1 = wf[i * 2 + 1];
            a[0] = fmaf(xv, w0.x, a[0]); a[1] = fmaf(xv, w0.y, a[1]);
            a[2] = fmaf(xv, w0.z, a[2]); a[3] = fmaf(xv, w0.w, a[3]);
            a[4] = fmaf(xv, w1.x, a[4]); a[5] = fmaf(xv, w1.y, a[5]);
            a[6] = fmaf(xv, w1.z, a[6]); a[7] = fmaf(xv, w1.w, a[7]);
        }
        uint4 s;
        s.x = bf16_pack2(a[0], a[1]); s.y = bf16_pack2(a[2], a[3]);
        s.z = bf16_pack2(a[4], a[5]); s.w = bf16_pack2(a[6], a[7]);
        // dword idx: row (b,c,r) = 8 dwords; lane order (oh,rl,c) -> wave
        // covers two contiguous 512-B spans -> clean full-line writes
        *(uint4*)(u + (((size_t)b * NC + c) * NR + r) * 8 + oh * 4) = s;
    }
}

// -------------------------------------------------------------------------
// Fused routing pass: block = one b, 1024 thr = 256 rl x 4 oq; 4.5 r-sweeps.
// mode 0: wgt=0.1 (applied at epilogue); mode 1: softmax(u.vsum), vsum+=v;
// mode 2: softmax(u.vsum), out=v.  One u-read; squash fused in epilogue.
__global__ __launch_bounds__(1024, 4) void caps_fused_kernel(
    const uint32_t* __restrict__ u, float* __restrict__ vsum,
    float* __restrict__ out, const int mode)
{
    const int b  = blockIdx.x;
    const int t  = threadIdx.x;
    const int oq = t & 3;     // o-quad
    const int rl = t >> 2;    // 0..255

    __shared__ float vss[160];
    __shared__ float sred[16][160];

    if (mode != 0 && t < 160) vss[t] = vsum[(size_t)b * 160 + t];
    __syncthreads();

    float acc[10][4];
#pragma unroll
    for (int c = 0; c < 10; ++c)
#pragma unroll
        for (int j = 0; j < 4; ++j) acc[c][j] = 0.f;

    // uint2 index for (c, r): ((b*10+c)*1152 + r)*4 + oq
    const uint2* ub = (const uint2*)u + (size_t)b * NC * NR * 4 + oq;

    for (int k = 0; k < 5; ++k) {
        if (k == 4 && rl >= 128) break;       // tail: waves 8-15 skip (uniform)
        const int r = k * 256 + rl;
        uint2 q[10];
#pragma unroll
        for (int c = 0; c < 10; ++c) q[c] = ub[((size_t)c * NR + r) * 4];

        if (mode != 0) {
            float lg[10];
#pragma unroll
            for (int c = 0; c < 10; ++c) {
                const float4 vq = *(const float4*)&vss[c * 16 + oq * 4];
                float d = __uint_as_float(q[c].x << 16) * vq.x;
                d = fmaf(__uint_as_float(q[c].x & 0xFFFF0000u), vq.y, d);
                d = fmaf(__uint_as_float(q[c].y << 16),         vq.z, d);
                d = fmaf(__uint_as_float(q[c].y & 0xFFFF0000u), vq.w, d);
                lg[c] = d;
            }
#pragma unroll
            for (int c = 0; c < 10; ++c) {    // finish o-dot across 4 oq lanes
                lg[c] += __shfl_xor(lg[c], 1);
                lg[c] += __shfl_xor(lg[c], 2);
            }
            float m = lg[0];
#pragma unroll
            for (int c = 1; c < 10; ++c) m = fmaxf(m, lg[c]);
            float wgt[10], ssum = 0.f;
#pragma unroll
            for (int c = 0; c < 10; ++c) { wgt[c] = __expf(lg[c] - m); ssum += wgt[c]; }
            const float inv = 1.f / ssum;
#pragma unroll
            for (int c = 0; c < 10; ++c) {
                const float wv = wgt[c] * inv;
                acc[c][0] = fmaf(wv, __uint_as_float(q[c].x << 16),         acc[c][0]);
                acc[c][1] = fmaf(wv, __uint_as_float(q[c].x & 0xFFFF0000u), acc[c][1]);
                acc[c][2] = fmaf(wv, __uint_as_float(q[c].y << 16),         acc[c][2]);
                acc[c][3] = fmaf(wv, __uint_as_float(q[c].y & 0xFFFF0000u), acc[c][3]);
            }
        } else {
#pragma unroll
            for (int c = 0; c < 10; ++c) {    // uniform weights: 0.1 at epilogue
                acc[c][0] += __uint_as_float(q[c].x << 16);
                acc[c][1] += __uint_as_float(q[c].x & 0xFFFF0000u);
                acc[c][2] += __uint_as_float(q[c].y << 16);
                acc[c][3] += __uint_as_float(q[c].y & 0xFFFF0000u);
            }
        }
    }

    // in-wave reduce over the 16 rl-lanes (tid bits 2..5)
#pragma unroll
    for (int off = 4; off <= 32; off <<= 1)
#pragma unroll
        for (int c = 0; c < 10; ++c)
#pragma unroll
            for (int j = 0; j < 4; ++j) acc[c][j] += __shfl_xor(acc[c][j], off);

    const int wv = t >> 6;
    if ((t & 63) < 4) {
#pragma unroll
        for (int c = 0; c < 10; ++c)
#pragma unroll
            for (int j = 0; j < 4; ++j)
                sred[wv][c * 16 + oq * 4 + j] = acc[c][j];
    }
    __syncthreads();

    if (t < 160) {
        float s = 0.f;
#pragma unroll
        for (int w = 0; w < 16; ++w) s += sred[w][t];
        if (mode == 0) s *= 0.1f;
        float n2 = s * s;                 // squash: ||s||^2 over o (t&15)
        n2 += __shfl_xor(n2, 1);
        n2 += __shfl_xor(n2, 2);
        n2 += __shfl_xor(n2, 4);
        n2 += __shfl_xor(n2, 8);
        const float nrm   = sqrtf(n2);
        const float scale = n2 / (1.f + n2) / (nrm + 1e-8f);
        const float v = scale * s;
        if (mode == 0)      vsum[(size_t)b * 160 + t] = v;
        else if (mode == 1) vsum[(size_t)b * 160 + t] = vss[t] + v;
        else                out[(size_t)b * 160 + t] = v;
    }
}

// -------------------------------------------------------------------------
extern "C" void kernel_launch(void* const* d_in, const int* in_sizes, int n_in,
                              void* d_out, int out_size, void* d_ws, size_t ws_size,
                              hipStream_t stream) {
    const float* x = (const float*)d_in[0];   // [256,1152,8]
    const float* W = (const float*)d_in[1];   // [1,1152,10,8,16]
    float* out = (float*)d_out;               // [256,10,16]

    // ws: u bf16 [B][C][R][O] = 94,371,840 B ; vsum f32 163,840 B
    uint8_t*  ws  = (uint8_t*)d_ws;
    uint32_t* u   = (uint32_t*)ws;
    float*    vsm = (float*)(ws + 94371840u);

    caps_u_kernel    <<<576, 320, 0, stream>>>(x, W, u);
    caps_fused_kernel<<<NB, 1024, 0, stream>>>(u, vsm, nullptr, 0);
    caps_fused_kernel<<<NB, 1024, 0, stream>>>(u, vsm, nullptr, 1);
    caps_fused_kernel<<<NB, 1024, 0, stream>>>(u, vsm, out,     2);
}

// Round 6
// 159.377 us; speedup vs baseline: 7.2262x; 1.8677x over previous
//
#include <hip/hip_runtime.h>
#include <cstdint>
#include <cstddef>

// DigitCapsules routing: B=256, R=1152, C=10, IC=8, OC=16, 3 iters.
// R6 (7 launches):
//   caps_u: u[b][c][r][o] bf16 (94 MB). thread=(c,r,oq): W = 32 floats in
//     regs (fits! R4/R5 died on launch_bounds-induced spills), x LDS-staged,
//     16-deep b-loop, 2304 blocks (11 waves/SIMD).
//   3x { caps_pass: 1536 blocks (256 b x 6 r-splits of 192), one u-read,
//        softmax thread-local-ish (2 shuffles), block partial -> part;
//        caps_reduce: 256 blocks, sum 6 partials + squash + vsum/out. }
// Logits linear in v: b_t = u.(v1+..+v_{t-1}) -> running vsum, 1 pass/iter.
// REGISTER DISCIPLINE: every kernel sized to fit its largest live set with
// launch_bounds cap >= 2x estimate (R2/R4/R5 all died on spills).
#define NB 256
#define NR 1152
#define NC 10
#define NI 8
#define NO 16
#define NSPLIT 6
#define RSPL 192   // r per split (3 sweeps of 64 rl)

static __device__ __forceinline__ uint32_t bf16_pack2(float lo, float hi) {
    uint32_t vl = __float_as_uint(lo);
    vl = vl + 0x7FFFu + ((vl >> 16) & 1u);
    uint32_t vh = __float_as_uint(hi);
    vh = vh + 0x7FFFu + ((vh >> 16) & 1u);
    return (vl >> 16) | (vh & 0xFFFF0000u);
}

// -------------------------------------------------------------------------
// caps_u: grid 2304 = 144 r-chunks(8) x 16 b-groups(16). 320 thr:
// t = c*32 + rl*4 + oq. W[r][c][i][oq*4..+3] = 8 float4 in regs.
__global__ __launch_bounds__(320, 2) void caps_u_kernel(
    const float* __restrict__ x, const float* __restrict__ W,
    uint32_t* __restrict__ u)
{
    const int t  = threadIdx.x;
    const int c  = t >> 5;             // 0..9
    const int rl = (t & 31) >> 2;      // 0..7
    const int oq = t & 3;              // 0..3
    const int rc = blockIdx.x >> 4;    // 0..143
    const int bg = blockIdx.x & 15;    // 0..15
    const int b0 = bg * 16;
    const int r  = rc * 8 + rl;

    __shared__ float xs[16][8][8];     // 4 KB

    if (t < 256) {                     // 256 float4 = x[b0..+16)[rc*8..+8)[8]
        const int bi = t >> 4, rem = t & 15;
        const int rr = rem >> 1, hf = rem & 1;
        *(float4*)&xs[bi][rr][hf * 4] =
            *(const float4*)(x + ((size_t)(b0 + bi) * NR + rc * 8 + rr) * 8 + hf * 4);
    }

    const float* wb = W + ((size_t)r * NC + c) * (NI * NO) + oq * 4;
    float4 wf[8];
#pragma unroll
    for (int i = 0; i < 8; ++i) wf[i] = *(const float4*)(wb + i * NO);

    __syncthreads();

    for (int bi = 0; bi < 16; ++bi) {
        float xr[8];
#pragma unroll
        for (int i = 0; i < 8; ++i) xr[i] = xs[bi][rl][i];
        float ax = 0.f, ay = 0.f, az = 0.f, aw = 0.f;
#pragma unroll
        for (int i = 0; i < 8; ++i) {
            const float xv = xr[i];
            ax = fmaf(xv, wf[i].x, ax); ay = fmaf(xv, wf[i].y, ay);
            az = fmaf(xv, wf[i].z, az); aw = fmaf(xv, wf[i].w, aw);
        }
        uint2 s;
        s.x = bf16_pack2(ax, ay);
        s.y = bf16_pack2(az, aw);
        // wave = 2 c-groups x (8 rl x 4 oq) -> two contiguous 256-B spans
        *(uint2*)(u + (((size_t)(b0 + bi) * NC + c) * NR + r) * 8 + oq * 2) = s;
    }
}

// -------------------------------------------------------------------------
// One routing pass over one r-split. 256 thr = 64 rl x 4 oq, 3 sweeps.
// mode 0: uniform weights (0.1 applied at epilogue). mode 1: softmax(u.vsum).
// Writes pre-squash partial s to part[sp][b][160]. No atomics.
__global__ __launch_bounds__(256, 2) void caps_pass_kernel(
    const uint32_t* __restrict__ u, const float* __restrict__ vsum,
    float* __restrict__ part, const int mode)
{
    const int b  = blockIdx.x / NSPLIT;
    const int sp = blockIdx.x % NSPLIT;
    const int t  = threadIdx.x;
    const int oq = t & 3;
    const int rl = t >> 2;    // 0..63

    __shared__ float vss[160];
    __shared__ float sred[4][160];

    if (mode != 0 && t < 160) vss[t] = vsum[(size_t)b * 160 + t];
    __syncthreads();

    float acc[10][4];
#pragma unroll
    for (int c = 0; c < 10; ++c)
#pragma unroll
        for (int j = 0; j < 4; ++j) acc[c][j] = 0.f;

    const uint2* ub = (const uint2*)u + (size_t)b * NC * NR * 4 + oq;

    for (int k = 0; k < 3; ++k) {
        const int r = sp * RSPL + k * 64 + rl;
        uint2 q[10];
#pragma unroll
        for (int c = 0; c < 10; ++c) q[c] = ub[((size_t)c * NR + r) * 4];

        if (mode != 0) {
            float lg[10];
#pragma unroll
            for (int c = 0; c < 10; ++c) {
                const float4 vq = *(const float4*)&vss[c * 16 + oq * 4];
                float d = __uint_as_float(q[c].x << 16) * vq.x;
                d = fmaf(__uint_as_float(q[c].x & 0xFFFF0000u), vq.y, d);
                d = fmaf(__uint_as_float(q[c].y << 16),         vq.z, d);
                d = fmaf(__uint_as_float(q[c].y & 0xFFFF0000u), vq.w, d);
                lg[c] = d;
            }
#pragma unroll
            for (int c = 0; c < 10; ++c) {    // finish o-dot over 4 oq lanes
                lg[c] += __shfl_xor(lg[c], 1);
                lg[c] += __shfl_xor(lg[c], 2);
            }
            float m = lg[0];
#pragma unroll
            for (int c = 1; c < 10; ++c) m = fmaxf(m, lg[c]);
            float wgt[10], ssum = 0.f;
#pragma unroll
            for (int c = 0; c < 10; ++c) { wgt[c] = __expf(lg[c] - m); ssum += wgt[c]; }
            const float inv = 1.f / ssum;
#pragma unroll
            for (int c = 0; c < 10; ++c) {
                const float wv = wgt[c] * inv;
                acc[c][0] = fmaf(wv, __uint_as_float(q[c].x << 16),         acc[c][0]);
                acc[c][1] = fmaf(wv, __uint_as_float(q[c].x & 0xFFFF0000u), acc[c][1]);
                acc[c][2] = fmaf(wv, __uint_as_float(q[c].y << 16),         acc[c][2]);
                acc[c][3] = fmaf(wv, __uint_as_float(q[c].y & 0xFFFF0000u), acc[c][3]);
            }
        } else {
#pragma unroll
            for (int c = 0; c < 10; ++c) {
                acc[c][0] += __uint_as_float(q[c].x << 16);
                acc[c][1] += __uint_as_float(q[c].x & 0xFFFF0000u);
                acc[c][2] += __uint_as_float(q[c].y << 16);
                acc[c][3] += __uint_as_float(q[c].y & 0xFFFF0000u);
            }
        }
    }

    // in-wave reduce over 16 rl-lanes (tid bits 2..5)
#pragma unroll
    for (int off = 4; off <= 32; off <<= 1)
#pragma unroll
        for (int c = 0; c < 10; ++c)
#pragma unroll
            for (int j = 0; j < 4; ++j) acc[c][j] += __shfl_xor(acc[c][j], off);

    const int wv = t >> 6;
    if ((t & 63) < 4) {
#pragma unroll
        for (int c = 0; c < 10; ++c)
#pragma unroll
            for (int j = 0; j < 4; ++j)
                sred[wv][c * 16 + oq * 4 + j] = acc[c][j];
    }
    __syncthreads();

    if (t < 160) {
        float s = sred[0][t] + sred[1][t] + sred[2][t] + sred[3][t];
        if (mode == 0) s *= 0.1f;
        part[((size_t)sp * NB + b) * 160 + t] = s;
    }
}

// -------------------------------------------------------------------------
// sum NSPLIT partials + squash. grid=256 (b), 192 thr (160 active).
// mode 0: vsum = v ; 1: vsum += v ; 2: out = v
__global__ __launch_bounds__(192) void caps_reduce_kernel(
    const float* __restrict__ part, float* __restrict__ vsum,
    float* __restrict__ out, const int mode)
{
    const int b = blockIdx.x;
    const int t = threadIdx.x;
    if (t >= 160) return;
    float s = 0.f;
#pragma unroll
    for (int sp = 0; sp < NSPLIT; ++sp)
        s += part[((size_t)sp * NB + b) * 160 + t];
    float n2 = s * s;                 // squash over o (t & 15)
    n2 += __shfl_xor(n2, 1);
    n2 += __shfl_xor(n2, 2);
    n2 += __shfl_xor(n2, 4);
    n2 += __shfl_xor(n2, 8);
    const float nrm   = sqrtf(n2);
    const float scale = n2 / (1.f + n2) / (nrm + 1e-8f);
    const float v = scale * s;
    if (mode == 0)      vsum[(size_t)b * 160 + t] = v;
    else if (mode == 1) vsum[(size_t)b * 160 + t] += v;
    else                out[(size_t)b * 160 + t] = v;
}

// -------------------------------------------------------------------------
extern "C" void kernel_launch(void* const* d_in, const int* in_sizes, int n_in,
                              void* d_out, int out_size, void* d_ws, size_t ws_size,
                              hipStream_t stream) {
    const float* x = (const float*)d_in[0];   // [256,1152,8]
    const float* W = (const float*)d_in[1];   // [1,1152,10,8,16]
    float* out = (float*)d_out;               // [256,10,16]

    // ws: u bf16 94,371,840 B | part 6*256*160*4 = 983,040 B | vsum 163,840 B
    uint8_t*  ws  = (uint8_t*)d_ws;
    uint32_t* u   = (uint32_t*)ws;
    float*    prt = (float*)(ws + 94371840u);
    float*    vsm = (float*)(ws + 94371840u + 983040u);

    caps_u_kernel     <<<2304, 320, 0, stream>>>(x, W, u);
    caps_pass_kernel  <<<NB * NSPLIT, 256, 0, stream>>>(u, vsm, prt, 0);
    caps_reduce_kernel<<<NB, 192, 0, stream>>>(prt, vsm, nullptr, 0);
    caps_pass_kernel  <<<NB * NSPLIT, 256, 0, stream>>>(u, vsm, prt, 1);
    caps_reduce_kernel<<<NB, 192, 0, stream>>>(prt, vsm, nullptr, 1);
    caps_pass_kernel  <<<NB * NSPLIT, 256, 0, stream>>>(u, vsm, prt, 1);
    caps_reduce_kernel<<<NB, 192, 0, stream>>>(prt, nullptr, out, 2);
}